// Round 2
// baseline (55.639 us; speedup 1.0000x reference)
//
#include <hip/hip_runtime.h>
#include <hip/hip_bf16.h>
#include <math.h>

#define KBINS 5
#define NF 4
#define BV 3.0f

// ws float layout:
//   [0, 160):  per-flow per-bin table: f*40 + k*8 + {cw, iw, ch, h, d, dl, dr, s2}
//   [160,176): interior bin boundaries: f*4 + j = cumw[j+1], j=0..3
//   [176,179): mu, c0 (= -0.5*log(2pi) - 0.5*logvar), inv_var
#define BND_OFF 160
#define SCAL_OFF 176
#define TBL_FLOATS 176

__global__ void nsf_prep(const float* __restrict__ layers,
                         const float* __restrict__ ip,
                         float* __restrict__ ws) {
    const int f = threadIdx.x;
    if (f < NF) {
        const float* p = layers + f * (3 * KBINS - 1);
        float W[KBINS], H[KBINS];
        float mw = p[0];
        for (int i = 1; i < KBINS; ++i) mw = fmaxf(mw, p[i]);
        float sw = 0.f;
        float ew[KBINS], eh[KBINS];
        for (int i = 0; i < KBINS; ++i) { ew[i] = expf(p[i] - mw); sw += ew[i]; }
        for (int i = 0; i < KBINS; ++i) W[i] = (ew[i] / sw) * (2.f * BV);
        float mh = p[KBINS];
        for (int i = 1; i < KBINS; ++i) mh = fmaxf(mh, p[KBINS + i]);
        float sh = 0.f;
        for (int i = 0; i < KBINS; ++i) { eh[i] = expf(p[KBINS + i] - mh); sh += eh[i]; }
        for (int i = 0; i < KBINS; ++i) H[i] = (eh[i] / sh) * (2.f * BV);
        float derivs[KBINS + 1];
        derivs[0] = 1.f;
        derivs[KBINS] = 1.f;
        for (int i = 0; i < KBINS - 1; ++i)
            derivs[i + 1] = 2.f / (1.f + expf(-p[2 * KBINS + i]));
        // cumsum in f32 first, then subtract B (match jax op order)
        float csw = 0.f, csh = 0.f;
        for (int k = 0; k < KBINS; ++k) {
            float cw = csw - BV;   // cumw[k]
            float ch = csh - BV;   // cumh[k]
            float d = H[k] / W[k];
            float dl = derivs[k], dr = derivs[k + 1];
            float* t = ws + f * 40 + k * 8;
            t[0] = cw;
            t[1] = 1.f / W[k];
            t[2] = ch;
            t[3] = H[k];
            t[4] = d;
            t[5] = dl;
            t[6] = dr;
            t[7] = dl + dr - 2.f * d;
            csw += W[k];
            csh += H[k];
            if (k < KBINS - 1) ws[BND_OFF + f * 4 + k] = csw - BV;
        }
    }
    if (f == 0) {
        ws[SCAL_OFF + 0] = ip[0];
        ws[SCAL_OFF + 1] = -0.5f * logf(2.f * (float)M_PI) - 0.5f * ip[1];
        ws[SCAL_OFF + 2] = expf(-ip[1]);
    }
}

__device__ __forceinline__ void nsf_elem(float x, const float* __restrict__ tbl,
                                         float mu, float c0, float ivar,
                                         float& lp, float& ldout, float& xo) {
    float ldacc = 0.f;
#pragma unroll
    for (int f = 0; f < NF; ++f) {
        const bool inside = (x >= -BV) && (x <= BV);
        float xc = fminf(fmaxf(x, -BV), BV);
        const float* bb = &tbl[BND_OFF + f * 4];
        int k = (xc >= bb[0]) + (xc >= bb[1]) + (xc >= bb[2]) + (xc >= bb[3]);
        const float* t = &tbl[f * 40 + k * 8];
        float cw = t[0], iw = t[1], ch = t[2], h = t[3];
        float d = t[4], dl = t[5], dr = t[6], s2 = t[7];
        float th = (xc - cw) * iw;
        float omt = 1.f - th;
        float tomt = th * omt;
        float th2 = th * th;
        float den = fmaf(s2, tomt, d);
        float rden = __builtin_amdgcn_rcpf(den);
        float zin = fmaf(h * fmaf(d, th2, dl * tomt), rden, ch);
        float dnum = (d * d) * fmaf(dr, th2, fmaf(2.f * d, tomt, dl * (omt * omt)));
        float ldin = __logf(dnum * (rden * rden));
        x = inside ? zin : x;
        ldacc += inside ? ldin : 0.f;
    }
    float xm = x - mu;
    lp = fmaf(-0.5f * ivar, xm * xm, c0);
    ldout = ldacc;
    xo = x;
}

__global__ __launch_bounds__(256) void nsf_main(
    const float* __restrict__ xin,
    const float* __restrict__ ws,
    float* __restrict__ out,
    long n) {
    __shared__ float tbl[TBL_FLOATS];
    if (threadIdx.x < TBL_FLOATS / 4)
        reinterpret_cast<float4*>(tbl)[threadIdx.x] =
            reinterpret_cast<const float4*>(ws)[threadIdx.x];
    __syncthreads();
    const float mu = ws[SCAL_OFF + 0];
    const float c0 = ws[SCAL_OFF + 1];
    const float ivar = ws[SCAL_OFF + 2];

    const long n4 = n >> 2;
    const long idx0 = (long)blockIdx.x * blockDim.x + threadIdx.x;
    const long stride = (long)gridDim.x * blockDim.x;

    for (long c = idx0; c < n4; c += stride) {
        float4 xv = reinterpret_cast<const float4*>(xin)[c];
        float xs[4] = {xv.x, xv.y, xv.z, xv.w};
        float r_lp[4], r_ld[4], r_x[4];
#pragma unroll
        for (int e = 0; e < 4; ++e) {
            nsf_elem(xs[e], tbl, mu, c0, ivar, r_lp[e], r_ld[e], r_x[e]);
        }
        float4 v0 = {r_lp[0], r_lp[1], r_lp[2], r_lp[3]};
        float4 v1 = {r_ld[0], r_ld[1], r_ld[2], r_ld[3]};
        float4 v2 = {r_x[0], r_x[1], r_x[2], r_x[3]};
        reinterpret_cast<float4*>(out)[c] = v0;
        reinterpret_cast<float4*>(out + n)[c] = v1;
        reinterpret_cast<float4*>(out + 2 * n)[c] = v2;
    }
    // tail (n not divisible by 4)
    const long rem = n & 3;
    if (rem && idx0 < rem) {
        long i = n4 * 4 + idx0;
        float lp, ld, xo;
        nsf_elem(xin[i], tbl, mu, c0, ivar, lp, ld, xo);
        out[i] = lp;
        out[n + i] = ld;
        out[2 * n + i] = xo;
    }
}

extern "C" void kernel_launch(void* const* d_in, const int* in_sizes, int n_in,
                              void* d_out, int out_size, void* d_ws, size_t ws_size,
                              hipStream_t stream) {
    const float* x = (const float*)d_in[0];
    const float* layers = (const float*)d_in[1];
    const float* ip = (const float*)d_in[2];
    float* ws = (float*)d_ws;
    float* out = (float*)d_out;
    const long n = (long)in_sizes[0];

    hipLaunchKernelGGL(nsf_prep, dim3(1), dim3(64), 0, stream, layers, ip, ws);

    const long n4 = (n + 3) >> 2;
    int blocks = (int)((n4 + 255) / 256);
    if (blocks < 1) blocks = 1;
    hipLaunchKernelGGL(nsf_main, dim3(blocks), dim3(256), 0, stream, x, ws, out, n);
}

// Round 4
// 53.096 us; speedup vs baseline: 1.0479x; 1.0479x over previous
//
#include <hip/hip_runtime.h>
#include <hip/hip_bf16.h>
#include <math.h>

#define KBINS 5
#define NF 4
#define BV 3.0f

typedef float f32x4 __attribute__((ext_vector_type(4)));

// ws float layout:
//   [0, 160):  per-flow per-bin table: f*40 + k*8 + {cw, iw, ch, h, d, dl, dr, s2}
//   [160,176): interior bin boundaries: f*4 + j = cumw[j+1], j=0..3
//   [176,179): mu, c0 (= -0.5*log(2pi) - 0.5*logvar), inv_var
#define BND_OFF 160
#define SCAL_OFF 176
#define TBL_FLOATS 176

__global__ void nsf_prep(const float* __restrict__ layers,
                         const float* __restrict__ ip,
                         float* __restrict__ ws) {
    const int f = threadIdx.x;
    if (f < NF) {
        const float* p = layers + f * (3 * KBINS - 1);
        float W[KBINS], H[KBINS];
        float mw = p[0];
        for (int i = 1; i < KBINS; ++i) mw = fmaxf(mw, p[i]);
        float sw = 0.f;
        float ew[KBINS], eh[KBINS];
        for (int i = 0; i < KBINS; ++i) { ew[i] = expf(p[i] - mw); sw += ew[i]; }
        for (int i = 0; i < KBINS; ++i) W[i] = (ew[i] / sw) * (2.f * BV);
        float mh = p[KBINS];
        for (int i = 1; i < KBINS; ++i) mh = fmaxf(mh, p[KBINS + i]);
        float sh = 0.f;
        for (int i = 0; i < KBINS; ++i) { eh[i] = expf(p[KBINS + i] - mh); sh += eh[i]; }
        for (int i = 0; i < KBINS; ++i) H[i] = (eh[i] / sh) * (2.f * BV);
        float derivs[KBINS + 1];
        derivs[0] = 1.f;
        derivs[KBINS] = 1.f;
        for (int i = 0; i < KBINS - 1; ++i)
            derivs[i + 1] = 2.f / (1.f + expf(-p[2 * KBINS + i]));
        float csw = 0.f, csh = 0.f;
        for (int k = 0; k < KBINS; ++k) {
            float cw = csw - BV;
            float ch = csh - BV;
            float d = H[k] / W[k];
            float dl = derivs[k], dr = derivs[k + 1];
            float* t = ws + f * 40 + k * 8;
            t[0] = cw;
            t[1] = 1.f / W[k];
            t[2] = ch;
            t[3] = H[k];
            t[4] = d;
            t[5] = dl;
            t[6] = dr;
            t[7] = dl + dr - 2.f * d;
            csw += W[k];
            csh += H[k];
            if (k < KBINS - 1) ws[BND_OFF + f * 4 + k] = csw - BV;
        }
    }
    if (f == 0) {
        ws[SCAL_OFF + 0] = ip[0];
        ws[SCAL_OFF + 1] = -0.5f * logf(2.f * (float)M_PI) - 0.5f * ip[1];
        ws[SCAL_OFF + 2] = expf(-ip[1]);
    }
}

__global__ __launch_bounds__(256, 4) void nsf_main(
    const float* __restrict__ xin,
    const float* __restrict__ ws,
    float* __restrict__ out,
    long n) {
    __shared__ __align__(16) float tbl[TBL_FLOATS];
    if (threadIdx.x < TBL_FLOATS / 4)
        reinterpret_cast<float4*>(tbl)[threadIdx.x] =
            reinterpret_cast<const float4*>(ws)[threadIdx.x];
    __syncthreads();
    const float mu = ws[SCAL_OFF + 0];
    const float c0 = ws[SCAL_OFF + 1];
    const float ivar = ws[SCAL_OFF + 2];

    const long n4 = n >> 2;
    const long idx0 = (long)blockIdx.x * blockDim.x + threadIdx.x;

    if (idx0 < n4) {
        f32x4 xv = reinterpret_cast<const f32x4*>(xin)[idx0];
        float x[4] = {xv.x, xv.y, xv.z, xv.w};
        float lda[4] = {0.f, 0.f, 0.f, 0.f};

#pragma unroll
        for (int f = 0; f < NF; ++f) {
            // boundaries for this flow (uniform; one b128)
            const float4 bb = *reinterpret_cast<const float4*>(&tbl[BND_OFF + f * 4]);
            // phase 1: bin search + issue all table reads (2 b128 per elem)
            float xc[4];
            float4 lo[4], hi[4];
#pragma unroll
            for (int e = 0; e < 4; ++e) {
                xc[e] = fminf(fmaxf(x[e], -BV), BV);
                int k = (xc[e] >= bb.x) + (xc[e] >= bb.y) + (xc[e] >= bb.z) + (xc[e] >= bb.w);
                const float4* t = reinterpret_cast<const float4*>(&tbl[f * 40 + k * 8]);
                lo[e] = t[0];
                hi[e] = t[1];
            }
            // phase 2: math
#pragma unroll
            for (int e = 0; e < 4; ++e) {
                const bool inside = (x[e] >= -BV) && (x[e] <= BV);
                float cw = lo[e].x, iw = lo[e].y, ch = lo[e].z, h = lo[e].w;
                float d = hi[e].x, dl = hi[e].y, dr = hi[e].z, s2 = hi[e].w;
                float th = (xc[e] - cw) * iw;
                float omt = 1.f - th;
                float tomt = th * omt;
                float th2 = th * th;
                float den = fmaf(s2, tomt, d);
                float rden = __builtin_amdgcn_rcpf(den);
                float zin = fmaf(h * fmaf(d, th2, dl * tomt), rden, ch);
                float dnum = (d * d) * fmaf(dr, th2, fmaf(2.f * d, tomt, dl * (omt * omt)));
                float ldin = __logf(dnum * (rden * rden));
                x[e] = inside ? zin : x[e];
                lda[e] += inside ? ldin : 0.f;
            }
        }

        f32x4 v0, v1, v2;
#pragma unroll
        for (int e = 0; e < 4; ++e) {
            float xm = x[e] - mu;
            v0[e] = fmaf(-0.5f * ivar, xm * xm, c0);
            v1[e] = lda[e];
            v2[e] = x[e];
        }
        __builtin_nontemporal_store(v0, reinterpret_cast<f32x4*>(out) + idx0);
        __builtin_nontemporal_store(v1, reinterpret_cast<f32x4*>(out + n) + idx0);
        __builtin_nontemporal_store(v2, reinterpret_cast<f32x4*>(out + 2 * n) + idx0);
    }

    // tail (n not divisible by 4)
    const long rem = n & 3;
    if (rem && idx0 < rem) {
        long i = n4 * 4 + idx0;
        float x = xin[i];
        float lda = 0.f;
#pragma unroll
        for (int f = 0; f < NF; ++f) {
            const bool inside = (x >= -BV) && (x <= BV);
            float xc = fminf(fmaxf(x, -BV), BV);
            const float* bbp = &tbl[BND_OFF + f * 4];
            int k = (xc >= bbp[0]) + (xc >= bbp[1]) + (xc >= bbp[2]) + (xc >= bbp[3]);
            const float* t = &tbl[f * 40 + k * 8];
            float th = (xc - t[0]) * t[1];
            float omt = 1.f - th, tomt = th * omt, th2 = th * th;
            float den = fmaf(t[7], tomt, t[4]);
            float rden = __builtin_amdgcn_rcpf(den);
            float zin = fmaf(t[3] * fmaf(t[4], th2, t[5] * tomt), rden, t[2]);
            float dnum = (t[4] * t[4]) * fmaf(t[6], th2, fmaf(2.f * t[4], tomt, t[5] * (omt * omt)));
            float ldin = __logf(dnum * (rden * rden));
            x = inside ? zin : x;
            lda += inside ? ldin : 0.f;
        }
        float xm = x - mu;
        out[i] = fmaf(-0.5f * ivar, xm * xm, c0);
        out[n + i] = lda;
        out[2 * n + i] = x;
    }
}

extern "C" void kernel_launch(void* const* d_in, const int* in_sizes, int n_in,
                              void* d_out, int out_size, void* d_ws, size_t ws_size,
                              hipStream_t stream) {
    const float* x = (const float*)d_in[0];
    const float* layers = (const float*)d_in[1];
    const float* ip = (const float*)d_in[2];
    float* ws = (float*)d_ws;
    float* out = (float*)d_out;
    const long n = (long)in_sizes[0];

    hipLaunchKernelGGL(nsf_prep, dim3(1), dim3(64), 0, stream, layers, ip, ws);

    const long n4 = (n + 3) >> 2;
    int blocks = (int)((n4 + 255) / 256);
    if (blocks < 1) blocks = 1;
    hipLaunchKernelGGL(nsf_main, dim3(blocks), dim3(256), 0, stream, x, ws, out, n);
}